// Round 12
// baseline (67.581 us; speedup 1.0000x reference)
//
#include <hip/hip_runtime.h>

// ExplicitLiePE via MFMA: y[b,s] = expm(A) @ x[b,s], A = sum_k r_k * 0.5*(L_k - L_k^T).
//
// Structure = round-6 (16-token groups, 4 waves/block row-split, dbuf LDS
// exchange, 2 waves/SIMD) -- best verified at 32.1us. r7-r11 closed: occupancy
// duplication, fat blocks, exchange elimination, VALU trim -- all null or
// regressions. Bottleneck confirmed: ~45 serial barrier phases/group.
//
// Round-12: DOUBLE-STEP Clenshaw -- one barrier advances TWO steps.
//   b_m     = a_m x + Z b_{m+1} + b_{m+2}
//   b_{m-1} = a_{m-1} x + a_m (Zx) + Z^2 b_{m+1} + Z b_{m+2} + b_{m+1}
// Z^2 = sum_k qk^2 Gk^2 + sum_{k<k'} qk qk' (Gk Gk' + Gk' Gk): 6 token-
// independent pair-product matrices, built once in the prepass. Zx: one extra
// exchange before the loop. Per double-iter: stage b1+b2 (one barrier), 12
// matrix contractions (72 MFMA/wave) vs 36 for two single steps -- the MFMA
// pipe has 3-4x headroom, phases halve 45 -> ~23. DS and VALU per 2 steps
// unchanged. Scalar Miller runs two sub-updates per iter (identical seed/gate
// sequence); f32 master state never passes through f16 -> precision unchanged.
// Renorm once per double-iter before staging (<=1 extra step growth ~15x,
// f16 max 65504 -- safe).
//
// Layouts (r6-verified):
//  - C/D: reg r of lane l = D[16*w + (l>>4)*4 + r][l&15].
//  - A/B k-slot: col 32kt + 8*(l>>4) + j; staged b = linear f16 b[0..63].
//  - frag f = p*8 + m2*2 + kt, p in 0..8 (0-2 gen G_k, 3-8 pairs
//    {G0^2,G1^2,G2^2,G0G1+G1G0,G0G2+G2G0,G1G2+G2G1}); hi at frag[f*512+l*8+j],
//    lo at +36864.
//  - staging: stage[buf][vec][prec][c][36 dwords].

typedef _Float16 half8 __attribute__((ext_vector_type(8)));
typedef __fp16 fp16x2 __attribute__((ext_vector_type(2)));
typedef float float4t __attribute__((ext_vector_type(4)));

union H2U { fp16x2 h; unsigned u; };

__device__ __forceinline__ unsigned pkrtz2(float a, float b) {
    H2U v; v.h = __builtin_amdgcn_cvt_pkrtz(a, b); return v.u;
}
__device__ __forceinline__ float h2lo(unsigned u) { H2U v; v.u = u; return (float)v.h[0]; }
__device__ __forceinline__ float h2hi(unsigned u) { H2U v; v.u = u; return (float)v.h[1]; }

#define FRAG_LO 36864   // f16 offset of lo-fragments (72 tiles * 512)

// ---------------- prep 1: skew-symmetrize into f32 scratch -------------------
__global__ void liepe_prep_skew(const float* __restrict__ L, float* __restrict__ skew)
{
    int t = blockIdx.x * 256 + threadIdx.x;
    if (t >= 12288) return;
    int k = t >> 12, rem = t & 4095, i = rem >> 6, j = rem & 63;
    skew[t] = L[k * 4096 + i * 64 + j] - L[k * 4096 + j * 64 + i];
}

// ---------------- prep 2: gen + pair-product fragments, f16 hi/lo ------------
// grid 36 = (p 0..8) x (m2 0..3); per block: 1024 elements (2 kt x 64 l x 8 j).
__global__ void liepe_prep_frags(const float* __restrict__ skew, _Float16* __restrict__ frag)
{
    const int p  = blockIdx.x >> 2;
    const int m2 = blockIdx.x & 3;
    __shared__ float Ga[4096], Gb[4096];
    int a = 0, b = 0;
    if (p >= 3) {
        const int pa[6] = {0, 1, 2, 0, 0, 1};
        const int pb[6] = {0, 1, 2, 1, 2, 2};
        a = pa[p - 3]; b = pb[p - 3];
        for (int idx = threadIdx.x; idx < 4096; idx += 256) {
            Ga[idx] = skew[a * 4096 + idx];
            Gb[idx] = skew[b * 4096 + idx];
        }
        __syncthreads();
    }
    #pragma unroll
    for (int e4 = 0; e4 < 4; ++e4) {
        int e = threadIdx.x * 4 + e4;
        int kt = e >> 9, rem = e & 511, l = rem >> 3, j = rem & 7;
        int i  = 16 * m2 + (l & 15);
        int kk = 32 * kt + 8 * (l >> 4) + j;
        float val;
        if (p < 3) {
            val = skew[p * 4096 + i * 64 + kk];
        } else if (a == b) {
            float acc = 0.f;
            for (int t2 = 0; t2 < 64; ++t2)
                acc += Ga[i * 64 + t2] * Ga[t2 * 64 + kk];
            val = acc;
        } else {
            float acc = 0.f;
            for (int t2 = 0; t2 < 64; ++t2)
                acc += Ga[i * 64 + t2] * Gb[t2 * 64 + kk]
                     + Gb[i * 64 + t2] * Ga[t2 * 64 + kk];
            val = acc;
        }
        _Float16 h = (_Float16)val;
        int f = p * 8 + m2 * 2 + kt;
        frag[f * 512 + l * 8 + j] = h;
        frag[FRAG_LO + f * 512 + l * 8 + j] = (_Float16)(val - (float)h);
    }
}

// ---------------- main kernel: 4 waves/block, 16 tokens, double-step ---------

#define PSTR 36

#define STAGE_VEC(VEC, BV)                                                    \
  { unsigned h0 = pkrtz2(BV[0], BV[1]);                                       \
    unsigned h1 = pkrtz2(BV[2], BV[3]);                                       \
    unsigned l0 = pkrtz2(BV[0] - h2lo(h0), BV[1] - h2hi(h0));                 \
    unsigned l1 = pkrtz2(BV[2] - h2lo(h1), BV[3] - h2hi(h1));                 \
    const int di = 8 * w + 2 * g;                                             \
    *(uint2*)&stage[buf][VEC][0][c][di] = make_uint2(h0, h1);                 \
    *(uint2*)&stage[buf][VEC][1][c][di] = make_uint2(l0, l1); }

#define LOAD_VEC(VEC, BH, BL)                                                 \
  { _Pragma("unroll")                                                         \
    for (int kt = 0; kt < 2; ++kt) {                                          \
      BH[kt] = *(const half8*)&stage[buf][VEC][0][c][16 * kt + 4 * g];        \
      BL[kt] = *(const half8*)&stage[buf][VEC][1][c][16 * kt + 4 * g];        \
    } }

// one matrix contraction: 3-term hi/lo, kt-split acc chains, scale-add by Q.
#define MAT_ACC(P, BH, BL, Q, TOUT, FIRST)                                    \
  { float4t ac0 = {0.f, 0.f, 0.f, 0.f};                                       \
    float4t ac1 = {0.f, 0.f, 0.f, 0.f};                                       \
    ac0 = __builtin_amdgcn_mfma_f32_16x16x32_f16(Ah[(P)*2+0], BH[0], ac0, 0, 0, 0); \
    ac1 = __builtin_amdgcn_mfma_f32_16x16x32_f16(Ah[(P)*2+1], BH[1], ac1, 0, 0, 0); \
    ac0 = __builtin_amdgcn_mfma_f32_16x16x32_f16(Ah[(P)*2+0], BL[0], ac0, 0, 0, 0); \
    ac1 = __builtin_amdgcn_mfma_f32_16x16x32_f16(Ah[(P)*2+1], BL[1], ac1, 0, 0, 0); \
    ac0 = __builtin_amdgcn_mfma_f32_16x16x32_f16(Al[(P)*2+0], BH[0], ac0, 0, 0, 0); \
    ac1 = __builtin_amdgcn_mfma_f32_16x16x32_f16(Al[(P)*2+1], BH[1], ac1, 0, 0, 0); \
    _Pragma("unroll")                                                         \
    for (int r4 = 0; r4 < 4; ++r4) {                                          \
      float sum = ac0[r4] + ac1[r4];                                          \
      if (FIRST) TOUT[r4] = (Q) * sum;                                        \
      else       TOUT[r4] = fmaf((Q), sum, TOUT[r4]);                         \
    } }

#define GEMM_Z(BH, BL, TOUT)                                                  \
  MAT_ACC(0, BH, BL, q0, TOUT, true)                                          \
  MAT_ACC(1, BH, BL, q1, TOUT, false)                                         \
  MAT_ACC(2, BH, BL, q2, TOUT, false)

__global__ __launch_bounds__(256)
__attribute__((amdgpu_waves_per_eu(1, 2)))
void liepe_mfma(
    const float* __restrict__ x,
    const float* __restrict__ r_grid,
    const _Float16* __restrict__ frag,
    float* __restrict__ out,
    int n_tokens)
{
    __shared__ __align__(16) unsigned stage[2][2][2][16][PSTR];  // 36KB

    const int lane = threadIdx.x & 63;
    const int w    = threadIdx.x >> 6;   // row-slice / m2 tile, 0..3
    const int c    = lane & 15;          // token column
    const int g    = lane >> 4;          // k-group / row sub-block

    int tok = blockIdx.x * 16 + c;
    if (tok >= n_tokens) tok = n_tokens - 1;

    // A-fragments for this wave's row slice: 9 matrices x 2 kt x hi/lo.
    half8 Ah[18], Al[18];
    #pragma unroll
    for (int p = 0; p < 9; ++p) {
        #pragma unroll
        for (int kt = 0; kt < 2; ++kt) {
            const int f = p * 8 + w * 2 + kt;
            Ah[p * 2 + kt] = *(const half8*)(frag + f * 512 + lane * 8);
            Al[p * 2 + kt] = *(const half8*)(frag + FRAG_LO + f * 512 + lane * 8);
        }
    }

    // x slice in D-layout: xv[r4] = x[tok][16w + 4g + r4].
    float xv[4];
    {
        float4 v = *(const float4*)(x + tok * 64 + 16 * w + 4 * g);
        xv[0] = v.x; xv[1] = v.y; xv[2] = v.z; xv[3] = v.w;
    }

    // Per-token scalars — identical in all 4 waves.
    const float r0 = r_grid[tok * 3 + 0];
    const float r1 = r_grid[tok * 3 + 1];
    const float r2 = r_grid[tok * 3 + 2];
    const float sig2 = 0.5f * (r0 * r0 + r1 * r1 + r2 * r2);
    const float rho  = fmaf(17.3f, __builtin_sqrtf(sig2), 2.0f);
    const float inv_rho = 1.0f / rho;
    const int   M  = (int)rho + 14;     // >= ceil(rho)+13 -> tail ~1e-4
    const int   ms = M + 10;
    const float q0 = r0 * inv_rho, q1 = r1 * inv_rho, q2 = r2 * inv_rho;
    const float p00 = q0 * q0, p11 = q1 * q1, p22 = q2 * q2;
    const float p01 = q0 * q1, p02 = q0 * q2, p12 = q1 * q2;

    int maxM = M;
    #pragma unroll
    for (int off = 1; off < 64; off <<= 1)
        maxM = max(maxM, __shfl_xor(maxM, off));

    float jp = 0.f, jc = 0.f, N = 0.f;

    // ---- descent: Miller only (scalar, no barriers) ----
    #pragma unroll 1
    for (int m = maxM + 10; m > maxM; --m) {
        bool sd = (m == ms);
        jc = sd ? 1e-12f : jc;
        jp = sd ? 0.f : jp;
        N  = sd ? (((m & 1) == 0) ? 2e-12f : 0.f) : N;
        float s = (jc > 1.0f) ? __builtin_amdgcn_rcpf(jc) : 1.0f;
        jc *= s; jp *= s; N *= s;
        float jm = fmaf((2.f * (float)m) * inv_rho, jc, -jp);
        jp = jc; jc = jm;
        int mm = m - 1;
        if ((mm & 1) == 0) N += (mm > 0) ? (jm + jm) : jm;
    }

    int buf = 0;

    // ---- Zx = Z.x, one exchange + gen GEMM ----
    float zx[4];
    {
        STAGE_VEC(0, xv);
        __syncthreads();
        half8 Xh[2], Xl[2];
        LOAD_VEC(0, Xh, Xl);
        GEMM_Z(Xh, Xl, zx);
        buf = 1;
    }

    float B1v[4] = {0.f, 0.f, 0.f, 0.f};   // b_{m+1}
    float B2v[4] = {0.f, 0.f, 0.f, 0.f};   // b_{m+2}

    // ---- main double-step loop: 1 barrier per 2 Clenshaw steps ----
    int m = maxM;
    #pragma unroll 1
    while (m >= 2) {
        bool sd = (m == ms);
        jc = sd ? 1e-12f : jc;
        jp = sd ? 0.f : jp;
        N  = sd ? (((m & 1) == 0) ? 2e-12f : 0.f) : N;

        float s = (jc > 1.0f) ? __builtin_amdgcn_rcpf(jc) : 1.0f;
        jc *= s; jp *= s; N *= s;
        #pragma unroll
        for (int i = 0; i < 4; ++i) { B1v[i] *= s; B2v[i] *= s; }

        STAGE_VEC(0, B1v);
        STAGE_VEC(1, B2v);
        __syncthreads();
        half8 B1h[2], B1l[2], B2h[2], B2l[2];
        LOAD_VEC(0, B1h, B1l);
        LOAD_VEC(1, B2h, B2l);
        buf ^= 1;

        float u[4];   // Z b_{m+1}
        GEMM_Z(B1h, B1l, u);
        float vw[4];  // Z^2 b_{m+1} + Z b_{m+2}
        MAT_ACC(3, B1h, B1l, p00, vw, true)
        MAT_ACC(4, B1h, B1l, p11, vw, false)
        MAT_ACC(5, B1h, B1l, p22, vw, false)
        MAT_ACC(6, B1h, B1l, p01, vw, false)
        MAT_ACC(7, B1h, B1l, p02, vw, false)
        MAT_ACC(8, B1h, B1l, p12, vw, false)
        MAT_ACC(0, B2h, B2l, q0, vw, false)
        MAT_ACC(1, B2h, B2l, q1, vw, false)
        MAT_ACC(2, B2h, B2l, q2, vw, false)

        // sub-step m
        float cfm = (m <= M) ? (jc + jc) : 0.f;
        float jm = fmaf((2.f * (float)m) * inv_rho, jc, -jp);
        jp = jc; jc = jm;
        { int mm = m - 1; if ((mm & 1) == 0) N += (mm > 0) ? (jm + jm) : jm; }

        // sub-step m-1 (seed may land here)
        bool sd1 = ((m - 1) == ms);
        jc = sd1 ? 1e-12f : jc;
        jp = sd1 ? 0.f : jp;
        N  = sd1 ? ((((m - 1) & 1) == 0) ? 2e-12f : 0.f) : N;
        float cfm1 = ((m - 1) <= M) ? (jc + jc) : 0.f;

        float nbm[4], nbm1[4];
        #pragma unroll
        for (int i = 0; i < 4; ++i) {
            nbm[i]  = fmaf(cfm,  xv[i], u[i] + B2v[i]);                       // b_m
            nbm1[i] = fmaf(cfm1, xv[i], fmaf(cfm, zx[i], vw[i] + B1v[i]));    // b_{m-1}
        }

        jm = fmaf((2.f * (float)(m - 1)) * inv_rho, jc, -jp);
        jp = jc; jc = jm;
        { int mm = m - 2; if ((mm & 1) == 0) N += (mm > 0) ? (jm + jm) : jm; }

        #pragma unroll
        for (int i = 0; i < 4; ++i) { B2v[i] = nbm[i]; B1v[i] = nbm1[i]; }
        m -= 2;
    }

    // ---- leftover single step (maxM odd): m == 1; ms >= 26 so no seed here ----
    if (m == 1) {
        float s = (jc > 1.0f) ? __builtin_amdgcn_rcpf(jc) : 1.0f;
        jc *= s; jp *= s; N *= s;
        #pragma unroll
        for (int i = 0; i < 4; ++i) { B1v[i] *= s; B2v[i] *= s; }
        STAGE_VEC(0, B1v);
        __syncthreads();
        half8 B1h[2], B1l[2];
        LOAD_VEC(0, B1h, B1l);
        buf ^= 1;
        float u[4];
        GEMM_Z(B1h, B1l, u);
        float cf = jc + jc;                 // m=1 <= M always
        float nb[4];
        #pragma unroll
        for (int i = 0; i < 4; ++i) nb[i] = fmaf(cf, xv[i], u[i] + B2v[i]);
        float jm = fmaf(2.f * inv_rho, jc, -jp);
        jp = jc; jc = jm;
        N += jm;                            // mm = 0
        #pragma unroll
        for (int i = 0; i < 4; ++i) { B2v[i] = B1v[i]; B1v[i] = nb[i]; }
    }

    // ---- final: b0 = J0 x + Z b_1 + b_2;  y = (b0 - 0.5*(Z b_1)) / N ----
    {
        float s = (jc > 1.0f) ? __builtin_amdgcn_rcpf(jc) : 1.0f;
        jc *= s; jp *= s; N *= s;
        #pragma unroll
        for (int i = 0; i < 4; ++i) { B1v[i] *= s; B2v[i] *= s; }
        STAGE_VEC(0, B1v);
        __syncthreads();
        half8 B1h[2], B1l[2];
        LOAD_VEC(0, B1h, B1l);
        float t[4];
        GEMM_Z(B1h, B1l, t);
        float4 v;
        v.x = (fmaf(jc, xv[0], t[0] + B2v[0]) - 0.5f * t[0]) / N;
        v.y = (fmaf(jc, xv[1], t[1] + B2v[1]) - 0.5f * t[1]) / N;
        v.z = (fmaf(jc, xv[2], t[2] + B2v[2]) - 0.5f * t[2]) / N;
        v.w = (fmaf(jc, xv[3], t[3] + B2v[3]) - 0.5f * t[3]) / N;
        *(float4*)(out + tok * 64 + 16 * w + 4 * g) = v;
    }
}

extern "C" void kernel_launch(void* const* d_in, const int* in_sizes, int n_in,
                              void* d_out, int out_size, void* d_ws, size_t ws_size,
                              hipStream_t stream) {
    const float* x = (const float*)d_in[0];
    const float* r = (const float*)d_in[1];
    const float* L = (const float*)d_in[2];
    // d_in[3] = P_sp: identity (allow_mixing=False) -> R_eff = R_r.
    float* out = (float*)d_out;

    float*     skew = (float*)d_ws;                  // 48KB f32 skew scratch
    _Float16*  frag = (_Float16*)d_ws + 24576;       // 144KB fragments (hi+lo)

    int n_tokens = in_sizes[0] / 64;   // B*S = 8192

    liepe_prep_skew<<<48, 256, 0, stream>>>(L, skew);
    liepe_prep_frags<<<36, 256, 0, stream>>>(skew, frag);

    int nwg = (n_tokens + 15) / 16;
    liepe_mfma<<<nwg, 256, 0, stream>>>(x, r, frag, out, n_tokens);
}

// Round 13
// 30.832 us; speedup vs baseline: 2.1919x; 2.1919x over previous
//
#include <hip/hip_runtime.h>

// ExplicitLiePE via MFMA: y[b,s] = expm(A) @ x[b,s], A = sum_k r_k * 0.5*(L_k - L_k^T).
//
// Structure = round-6 (best verified: 32.1us): 16-token groups, 4 waves/block
// row-split (wave w owns D-rows [16w,16w+16)), dbuf LDS b-exchange, 1 barrier
// per Clenshaw step, 512 blocks -> 2048 waves = 2/SIMD (grid-limited).
// Closed alternatives (all regressed or null): r7/r8 column-duplication (46us),
// r9 fat blocks/1 wave/SIMD (37.7us), r10 register-only no-exchange (47.5us),
// r11 conditional renorm (33.6us), r12 double-step Clenshaw w/ Z^2 (55.4us --
// fewer barriers but >2x serial work per barrier).
//
// Round-13 change: prep kernel ELIMINATED. Each wave builds its own 12
// A-fragments inline from L_param in the prologue (96 scattered f32 loads per
// lane, L2-resident after the first blocks, one-time ~0.2us) -- removes the
// separate prep launch + inter-kernel bubble (~4-5us of the r5/r6 bench-vs-main
// gap) and the d_ws dependency. Fragment values bit-identical to the prep
// version -> absmax unchanged (0.015625).
//
// Math (r6-verified): 16 tokens/block advance in lockstep;
//   G_k = (L_k - L_k^T).B, t[:,c] = sum_k (r_k[c]/rho_c) G_k[:,c]
// via v_mfma_f32_16x16x32_f16 with f16 hi/lo split of both L' and b
// (Lhi.bhi + Lhi.blo + Llo.bhi; dropped term ~2^-24). Miller's unnormalized
// scale tamed by per-step renorm s = jc>1 ? rcp(jc) : 1 (result is
// scale-invariant). Per-token seeding at m==ms, coeff gated by m<=M.
//
// Layouts:
//  - C/D: reg r of lane l = D[16*w + (l>>4)*4 + r][l&15] (HW-verified m89/m91).
//  - A/B k-slot bijection k = 8*(l>>4)+j within each K=32 tile.
//  - staging: stage[buf][hi/lo][token c][dword]; token stride 36 dwords.

typedef _Float16 half8 __attribute__((ext_vector_type(8)));
typedef __fp16 fp16x2 __attribute__((ext_vector_type(2)));
typedef float float4t __attribute__((ext_vector_type(4)));

union H2U { fp16x2 h; unsigned u; };

__device__ __forceinline__ unsigned pkrtz2(float a, float b) {
    H2U v; v.h = __builtin_amdgcn_cvt_pkrtz(a, b); return v.u;
}
__device__ __forceinline__ float h2lo(unsigned u) { H2U v; v.u = u; return (float)v.h[0]; }
__device__ __forceinline__ float h2hi(unsigned u) { H2U v; v.u = u; return (float)v.h[1]; }

// ---------------- main kernel: 4 waves per block, 16 tokens per block --------

#define PSTR 36   // token stride in dwords (b128-aligned reads)

// stage own b1 slice (hi/lo f16), sync, load full-K B fragments, flip buffer.
#define STAGE_AND_LOAD_B()                                                       \
  {                                                                              \
    unsigned h0 = pkrtz2(b1[0], b1[1]);                                          \
    unsigned h1 = pkrtz2(b1[2], b1[3]);                                          \
    unsigned l0 = pkrtz2(b1[0] - h2lo(h0), b1[1] - h2hi(h0));                    \
    unsigned l1 = pkrtz2(b1[2] - h2lo(h1), b1[3] - h2hi(h1));                    \
    const int di = 8 * w + 2 * g;                                                \
    *(uint2*)&stage[buf][0][c][di] = make_uint2(h0, h1);                         \
    *(uint2*)&stage[buf][1][c][di] = make_uint2(l0, l1);                         \
    __syncthreads();                                                             \
    _Pragma("unroll")                                                            \
    for (int kt = 0; kt < 2; ++kt) {                                             \
      Bh[kt] = *(const half8*)&stage[buf][0][c][16 * kt + 4 * g];                \
      Bl[kt] = *(const half8*)&stage[buf][1][c][16 * kt + 4 * g];                \
    }                                                                            \
    buf ^= 1;                                                                    \
  }

// 18 MFMAs for this wave's 16-row tile; kt-split accumulators (6 short chains).
#define GEMM_COMBINE(TOUT)                                                       \
  {                                                                              \
    _Pragma("unroll")                                                            \
    for (int gen = 0; gen < 3; ++gen) {                                          \
      float q = (gen == 0) ? q0 : ((gen == 1) ? q1 : q2);                        \
      float4t ac0 = {0.f, 0.f, 0.f, 0.f};                                        \
      float4t ac1 = {0.f, 0.f, 0.f, 0.f};                                        \
      ac0 = __builtin_amdgcn_mfma_f32_16x16x32_f16(Ah[gen*2+0], Bh[0], ac0, 0, 0, 0); \
      ac1 = __builtin_amdgcn_mfma_f32_16x16x32_f16(Ah[gen*2+1], Bh[1], ac1, 0, 0, 0); \
      ac0 = __builtin_amdgcn_mfma_f32_16x16x32_f16(Ah[gen*2+0], Bl[0], ac0, 0, 0, 0); \
      ac1 = __builtin_amdgcn_mfma_f32_16x16x32_f16(Ah[gen*2+1], Bl[1], ac1, 0, 0, 0); \
      ac0 = __builtin_amdgcn_mfma_f32_16x16x32_f16(Al[gen*2+0], Bh[0], ac0, 0, 0, 0); \
      ac1 = __builtin_amdgcn_mfma_f32_16x16x32_f16(Al[gen*2+1], Bh[1], ac1, 0, 0, 0); \
      _Pragma("unroll")                                                          \
      for (int r4 = 0; r4 < 4; ++r4) {                                           \
        float sum = ac0[r4] + ac1[r4];                                           \
        if (gen == 0) TOUT[r4] = q * sum;                                        \
        else          TOUT[r4] = fmaf(q, sum, TOUT[r4]);                         \
      }                                                                          \
    }                                                                            \
  }

__global__ __launch_bounds__(256) void liepe_mfma(
    const float* __restrict__ x,
    const float* __restrict__ r_grid,
    const float* __restrict__ L_param,
    float* __restrict__ out,
    int n_tokens)
{
    __shared__ __align__(16) unsigned stage[2][2][16][PSTR];  // 18KB

    const int lane = threadIdx.x & 63;
    const int w    = threadIdx.x >> 6;   // row-slice / m2 tile, 0..3
    const int c    = lane & 15;          // token column
    const int g    = lane >> 4;          // k-group / row sub-block

    int tok = blockIdx.x * 16 + c;
    if (tok >= n_tokens) tok = n_tokens - 1;

    // A-fragments for this wave's row slice (m2 = w), built INLINE from L:
    // element (lane, j) of tile (gen, kt) = L'[16w + (lane&15)][32kt + 8g + j],
    // L' = L - L^T. 6 hi + 6 lo half8 (48 VGPRs). One-time, L2-resident.
    half8 Ah[6], Al[6];
    {
        const int i = 16 * w + (lane & 15);
        #pragma unroll
        for (int gen = 0; gen < 3; ++gen) {
            const float* Lg = L_param + gen * 4096;
            #pragma unroll
            for (int kt = 0; kt < 2; ++kt) {
                const int kk0 = 32 * kt + 8 * g;
                half8 hi, lo;
                #pragma unroll
                for (int j = 0; j < 8; ++j) {
                    int kk = kk0 + j;
                    float d = Lg[i * 64 + kk] - Lg[kk * 64 + i];
                    _Float16 h = (_Float16)d;
                    hi[j] = h;
                    lo[j] = (_Float16)(d - (float)h);
                }
                Ah[gen * 2 + kt] = hi;
                Al[gen * 2 + kt] = lo;
            }
        }
    }

    // x slice in D-layout: xv[r4] = x[tok][16w + 4g + r4].
    float xv[4];
    {
        float4 v = *(const float4*)(x + tok * 64 + 16 * w + 4 * g);
        xv[0] = v.x; xv[1] = v.y; xv[2] = v.z; xv[3] = v.w;
    }

    // Per-token scalars — computed redundantly + identically in all 4 waves.
    const float r0 = r_grid[tok * 3 + 0];
    const float r1 = r_grid[tok * 3 + 1];
    const float r2 = r_grid[tok * 3 + 2];
    const float sig2 = 0.5f * (r0 * r0 + r1 * r1 + r2 * r2);
    const float rho  = fmaf(17.3f, __builtin_sqrtf(sig2), 2.0f);
    const float inv_rho = 1.0f / rho;
    const int   M  = (int)rho + 14;     // >= ceil(rho)+13 -> tail ~1e-4
    const int   ms = M + 10;
    const float q0 = r0 * inv_rho, q1 = r1 * inv_rho, q2 = r2 * inv_rho;

    // block max degree: wave-reduce suffices (every wave holds all 16 tokens).
    int maxM = M;
    #pragma unroll
    for (int off = 1; off < 64; off <<= 1)
        maxM = max(maxM, __shfl_xor(maxM, off));

    float jp = 0.f, jc = 0.f, N = 0.f;
    float b1[4] = {0.f, 0.f, 0.f, 0.f};
    float b2[4] = {0.f, 0.f, 0.f, 0.f};

    // ---- descent: Miller only (all b's exactly 0, no barriers needed) ----
    #pragma unroll 1
    for (int m = maxM + 10; m > maxM; --m) {
        bool sd = (m == ms);
        jc = sd ? 1e-12f : jc;
        jp = sd ? 0.f : jp;
        N  = sd ? (((m & 1) == 0) ? 2e-12f : 0.f) : N;
        float s = (jc > 1.0f) ? __builtin_amdgcn_rcpf(jc) : 1.0f;
        jc *= s; jp *= s; N *= s;
        float jm = fmaf((2.f * (float)m) * inv_rho, jc, -jp);
        jp = jc; jc = jm;
        int mm = m - 1;
        if ((mm & 1) == 0) N += (mm > 0) ? (jm + jm) : jm;
    }

    half8 Bh[2], Bl[2];
    int buf = 0;

    // ---- main fused Miller+Clenshaw loop (1 barrier per step, dbuf) ----
    #pragma unroll 1
    for (int m = maxM; m >= 1; --m) {
        bool sd = (m == ms);
        jc = sd ? 1e-12f : jc;
        jp = sd ? 0.f : jp;
        N  = sd ? (((m & 1) == 0) ? 2e-12f : 0.f) : N;

        // scale-invariant renorm: identical s in all 4 waves (same jc chain)
        float s = (jc > 1.0f) ? __builtin_amdgcn_rcpf(jc) : 1.0f;
        jc *= s; jp *= s; N *= s;
        #pragma unroll
        for (int i = 0; i < 4; ++i) { b1[i] *= s; b2[i] *= s; }

        STAGE_AND_LOAD_B();

        float t[4];
        GEMM_COMBINE(t);

        float cf = (m <= M) ? (jc + jc) : 0.f;
        #pragma unroll
        for (int i = 0; i < 4; ++i) {
            float bn = fmaf(cf, xv[i], t[i] + b2[i]);
            b2[i] = b1[i];
            b1[i] = bn;
        }

        float jm = fmaf((2.f * (float)m) * inv_rho, jc, -jp);
        jp = jc; jc = jm;
        int mm = m - 1;
        if ((mm & 1) == 0) N += (mm > 0) ? (jm + jm) : jm;
    }

    // ---- final: b0 = J0*x + (2A/rho)b1 + b2;  y = (b0 - 0.5*(2A/rho)b1)/N ----
    {
        STAGE_AND_LOAD_B();
        float t[4];
        GEMM_COMBINE(t);
        float4 v;
        float y0 = fmaf(jc, xv[0], t[0] + b2[0]);
        float y1 = fmaf(jc, xv[1], t[1] + b2[1]);
        float y2 = fmaf(jc, xv[2], t[2] + b2[2]);
        float y3 = fmaf(jc, xv[3], t[3] + b2[3]);
        v.x = (y0 - 0.5f * t[0]) / N;
        v.y = (y1 - 0.5f * t[1]) / N;
        v.z = (y2 - 0.5f * t[2]) / N;
        v.w = (y3 - 0.5f * t[3]) / N;
        *(float4*)(out + tok * 64 + 16 * w + 4 * g) = v;
    }
}

extern "C" void kernel_launch(void* const* d_in, const int* in_sizes, int n_in,
                              void* d_out, int out_size, void* d_ws, size_t ws_size,
                              hipStream_t stream) {
    const float* x = (const float*)d_in[0];
    const float* r = (const float*)d_in[1];
    const float* L = (const float*)d_in[2];
    // d_in[3] = P_sp: identity (allow_mixing=False) -> R_eff = R_r.
    float* out = (float*)d_out;

    int n_tokens = in_sizes[0] / 64;   // B*S = 8192

    int nwg = (n_tokens + 15) / 16;
    liepe_mfma<<<nwg, 256, 0, stream>>>(x, r, L, out, n_tokens);
}